// Round 2
// baseline (104.310 us; speedup 1.0000x reference)
//
#include <hip/hip_runtime.h>

#define BB 4
#define NN 8192
#define BN (BB * NN)
#define ALPHA 5.0f
#define EPSF 1e-12f
#define BLOCK 256
#define QPT 4              // queries per thread
#define QB (BLOCK * QPT)   // 1024 queries per block
#define BIGF 1e30f

// pair-transposed ref layout: one RefPk = 2 consecutive points
// {x0,x1, y0,y1, z0,z1, w0,w1}, w = 0.5*||p||^2
struct __align__(16) RefPk {
  float2 x, y, z, w;
};

__device__ __forceinline__ float fmin3f(float a, float b, float c) {
  float d;
  asm("v_min3_f32 %0, %1, %2, %3" : "=v"(d) : "v"(a), "v"(b), "v"(c));
  return d;
}

// prep: refs4[g] = (x,y,z,0.5||p||^2); refs_pk pair-transposed; zero counter.
__global__ __launch_bounds__(BLOCK) void prep_kernel(
    const float* __restrict__ xyz, float4* __restrict__ refs4,
    float* __restrict__ refs_pk, unsigned* __restrict__ counter) {
  int g = blockIdx.x * BLOCK + threadIdx.x;  // 0..BN-1
  if (g == 0) *counter = 0u;
  float x = xyz[3 * g + 0], y = xyz[3 * g + 1], z = xyz[3 * g + 2];
  float hpp = 0.5f * fmaf(x, x, fmaf(y, y, z * z));
  refs4[g] = make_float4(x, y, z, hpp);
  float* bp = refs_pk + (size_t)(g >> 1) * 8 + (g & 1);
  bp[0] = x;
  bp[2] = y;
  bp[4] = z;
  bp[6] = hpp;
}

#define U2 4  // RefPk per buffer = 8 refs per compute step

#define LOADPK(dst, J) \
  _Pragma("unroll") for (int k = 0; k < U2; k++) dst[k] = rp[(J) + k];

// top-1: per 2 refs per query: 3 pk_fma + 1 min3
#define COMP1(buf)                                                            \
  _Pragma("unroll") for (int k = 0; k < U2; k++) {                            \
    float2 rx = buf[k].x, ry = buf[k].y, rz = buf[k].z;                       \
    float2 w01 = buf[k].w; /* VGPR copy: frees the 1-SGPR slot for rx/ry/rz */\
    _Pragma("unroll") for (int i = 0; i < QPT; i++) {                         \
      float2 t;                                                               \
      asm("v_pk_fma_f32 %0, %1, %2, %3"                                       \
          : "=v"(t)                                                           \
          : "v"(nqx2[i]), "s"(rx), "v"(w01));                                 \
      asm("v_pk_fma_f32 %0, %1, %2, %0" : "+v"(t) : "v"(nqy2[i]), "s"(ry));  \
      asm("v_pk_fma_f32 %0, %1, %2, %0" : "+v"(t) : "v"(nqz2[i]), "s"(rz));  \
      asm("v_min3_f32 %0, %0, %1, %2"                                         \
          : "+v"(m1[i])                                                       \
          : "v"(t.x), "v"(t.y));                                              \
    }                                                                         \
  }

// top-2 (self blocks): second-smallest of {m1,m2,t0,t1} = min(m2,med3(m1,t0,t1))
#define COMP2(buf)                                                            \
  _Pragma("unroll") for (int k = 0; k < U2; k++) {                            \
    float2 rx = buf[k].x, ry = buf[k].y, rz = buf[k].z;                       \
    float2 w01 = buf[k].w;                                                    \
    _Pragma("unroll") for (int i = 0; i < QPT; i++) {                         \
      float2 t;                                                               \
      asm("v_pk_fma_f32 %0, %1, %2, %3"                                       \
          : "=v"(t)                                                           \
          : "v"(nqx2[i]), "s"(rx), "v"(w01));                                 \
      asm("v_pk_fma_f32 %0, %1, %2, %0" : "+v"(t) : "v"(nqy2[i]), "s"(ry));  \
      asm("v_pk_fma_f32 %0, %1, %2, %0" : "+v"(t) : "v"(nqz2[i]), "s"(rz));  \
      float med = __builtin_amdgcn_fmed3f(m1[i], t.x, t.y); /* old m1 */      \
      m2[i] = fminf(m2[i], med);                                              \
      asm("v_min3_f32 %0, %0, %1, %2"                                         \
          : "+v"(m1[i])                                                       \
          : "v"(t.x), "v"(t.y));                                              \
    }                                                                         \
  }

// pairs[s*BN + b*NN + q] = 0.5 * min_{r in seg s, r != q} d2(q,r)
// Self-pair (d2==0 exact) excluded; contributes sqrt(EPSF), added in merge.
template <int NSEG>
__global__ __launch_bounds__(BLOCK, 8) void knn_kernel(
    const float4* __restrict__ refs4, const RefPk* __restrict__ refs_pk,
    float* __restrict__ pairs) {
  constexpr int SEG = NN / NSEG;
  constexpr int HALF = SEG / 2;  // RefPk count per segment
  constexpr int CHUNKS = NN / QB;
  int bid = blockIdx.x;
  int s = bid % NSEG;
  int rem = bid / NSEG;
  int qchunk = rem % CHUNKS;
  int b = rem / CHUNKS;

  const float4* __restrict__ qb4 = refs4 + (size_t)b * NN;

  float2 nqx2[QPT], nqy2[QPT], nqz2[QPT];
  float hq[QPT], m1[QPT], m2[QPT];
#pragma unroll
  for (int i = 0; i < QPT; i++) {
    int q = qchunk * QB + threadIdx.x + i * BLOCK;
    float4 qp = qb4[q];  // coalesced vector load
    nqx2[i] = make_float2(-qp.x, -qp.x);
    nqy2[i] = make_float2(-qp.y, -qp.y);
    nqz2[i] = make_float2(-qp.z, -qp.z);
    hq[i] = qp.w;
    m1[i] = BIGF;
    m2[i] = BIGF;
  }

  // wave-uniform ref stream (SGPR s_load), explicit ping-pong double buffer.
  const RefPk* __restrict__ rp = refs_pk + ((size_t)b * NN + s * SEG) / 2;
  const bool self_block = ((s * SEG) / QB) == qchunk;

  RefPk bufA[U2], bufB[U2];
  LOADPK(bufA, 0);
  if (!self_block) {
    for (int j = 0; j < HALF; j += 2 * U2) {
      LOADPK(bufB, j + U2);
      COMP1(bufA);
      int jn = (j + 2 * U2 < HALF) ? (j + 2 * U2) : 0;
      LOADPK(bufA, jn);
      COMP1(bufB);
    }
  } else {
    for (int j = 0; j < HALF; j += 2 * U2) {
      LOADPK(bufB, j + U2);
      COMP2(bufA);
      int jn = (j + 2 * U2 < HALF) ? (j + 2 * U2) : 0;
      LOADPK(bufA, jn);
      COMP2(bufB);
    }
  }

#pragma unroll
  for (int i = 0; i < QPT; i++) {
    int q = qchunk * QB + threadIdx.x + i * BLOCK;
    float best = m1[i];
    if (self_block && (q / SEG) == s) best = m2[i];  // drop exact self-min
    pairs[(size_t)s * BN + b * NN + q] = best + hq[i];  // un-shift -> d2/2
  }
}

// merge + fused loss (last-block pattern): one thread per point.
#define MBLK 256
#define MGRID (BN / MBLK)  // 128 blocks; partials per batch = 32
template <int NSEG>
__global__ __launch_bounds__(MBLK) void merge_kernel(
    const float* __restrict__ pairs, float* __restrict__ dsum,
    float* __restrict__ partial, unsigned* __restrict__ counter,
    float* __restrict__ out) {
  int g = blockIdx.x * MBLK + threadIdx.x;  // 0 .. BN-1
  float m = BIGF;
#pragma unroll 8
  for (int s = 0; s < NSEG; s += 2) {
    float a = pairs[(size_t)s * BN + g];
    float c = pairs[(size_t)(s + 1) * BN + g];
    m = fmin3f(m, a, c);
  }
  // self term: reference sqrt(max(0,EPS)) == sqrt(EPSF), exact.
  float ds = sqrtf(fmaxf(m + m, EPSF)) + sqrtf(EPSF);
  dsum[g] = ds;

  float v = ds;
#pragma unroll
  for (int off = 32; off > 0; off >>= 1) v += __shfl_down(v, off, 64);
  __shared__ float warp_sums[MBLK / 64];
  if ((threadIdx.x & 63) == 0) warp_sums[threadIdx.x >> 6] = v;
  __syncthreads();
  if (threadIdx.x == 0) {
    float t = 0.0f;
#pragma unroll
    for (int w = 0; w < MBLK / 64; w++) t += warp_sums[w];
    partial[blockIdx.x] = t;
  }

  // ---- last-block loss (fence -> relaxed atomic -> fence publication) ----
  __threadfence();  // release: publish this thread's dsum (+ t0's partial)
  __shared__ int s_last;
  if (threadIdx.x == 0) {
    unsigned old = atomicAdd(counter, 1u);
    s_last = (old == (unsigned)(gridDim.x - 1));
  }
  __syncthreads();
  if (!s_last) return;
  __threadfence();  // acquire: all blocks' dsum/partial now visible

  __shared__ float s_avg[BB];
  float pv = 0.0f;
  if (threadIdx.x < MGRID) pv = partial[threadIdx.x];
#pragma unroll
  for (int off = 16; off > 0; off >>= 1) pv += __shfl_down(pv, off, 32);
  if (threadIdx.x < MGRID && (threadIdx.x & 31) == 0)
    s_avg[threadIdx.x >> 5] = pv * (ALPHA / NN);  // 32 partials per batch
  __syncthreads();

  const float4* d4 = (const float4*)dsum;
  float acc = 0.0f;
#pragma unroll
  for (int it = 0; it < BN / (MBLK * 4); it++) {  // 32 iters
    int idx = it * MBLK + threadIdx.x;            // float4 index
    float4 vv = d4[idx];
    float thr = s_avg[idx >> 11];  // 2048 float4 per batch
    acc += (vv.x > thr) ? vv.x : 0.0f;
    acc += (vv.y > thr) ? vv.y : 0.0f;
    acc += (vv.z > thr) ? vv.z : 0.0f;
    acc += (vv.w > thr) ? vv.w : 0.0f;
  }
#pragma unroll
  for (int off = 32; off > 0; off >>= 1) acc += __shfl_down(acc, off, 64);
  __shared__ float w2[MBLK / 64];
  if ((threadIdx.x & 63) == 0) w2[threadIdx.x >> 6] = acc;
  __syncthreads();
  if (threadIdx.x == 0) {
    float t = 0.0f;
#pragma unroll
    for (int w = 0; w < MBLK / 64; w++) t += w2[w];
    out[0] = t;
  }
}

template <int NSEG>
static void run(const float* xyz, float* out, void* d_ws, hipStream_t stream) {
  float* pairs = (float*)d_ws;
  float4* refs4 = (float4*)(pairs + (size_t)NSEG * BN);
  RefPk* refs_pk = (RefPk*)(refs4 + BN);
  float* dsum = (float*)(refs_pk + BN / 2);
  float* partial = dsum + BN;
  unsigned* counter = (unsigned*)(partial + MGRID);
  prep_kernel<<<BN / BLOCK, BLOCK, 0, stream>>>(xyz, refs4, (float*)refs_pk,
                                                counter);
  int grid1 = BB * (NN / QB) * NSEG;
  knn_kernel<NSEG><<<grid1, BLOCK, 0, stream>>>(refs4, refs_pk, pairs);
  merge_kernel<NSEG><<<BN / MBLK, MBLK, 0, stream>>>(pairs, dsum, partial,
                                                     counter, out);
}

extern "C" void kernel_launch(void* const* d_in, const int* in_sizes, int n_in,
                              void* d_out, int out_size, void* d_ws,
                              size_t ws_size, hipStream_t stream) {
  const float* xyz = (const float*)d_in[0];
  float* out = (float*)d_out;

  auto need = [](int nseg) {
    return (size_t)nseg * BN * sizeof(float) + BN * sizeof(float4) +
           (BN / 2) * sizeof(RefPk) + BN * sizeof(float) +
           MGRID * sizeof(float) + sizeof(unsigned);
  };
  if (ws_size >= need(64)) {
    run<64>(xyz, out, d_ws, stream);  // knn grid = 2048 blocks, 8/CU
  } else if (ws_size >= need(32)) {
    run<32>(xyz, out, d_ws, stream);
  } else {
    run<16>(xyz, out, d_ws, stream);
  }
}

// Round 3
// 97.341 us; speedup vs baseline: 1.0716x; 1.0716x over previous
//
#include <hip/hip_runtime.h>

#define BB 4
#define NN 8192
#define BN (BB * NN)
#define ALPHA 5.0f
#define EPSF 1e-12f
#define BLOCK 256
#define QPT 4              // queries per thread
#define QB (BLOCK * QPT)   // 1024 queries per block
#define BIGF 1e30f

__device__ __forceinline__ float fmin3f(float a, float b, float c) {
  float d;
  asm("v_min3_f32 %0, %1, %2, %3" : "=v"(d) : "v"(a), "v"(b), "v"(c));
  return d;
}

// prep: refs4[g] = (x, y, z, 0.5*||p||^2)
__global__ __launch_bounds__(BLOCK) void prep_kernel(
    const float* __restrict__ xyz, float4* __restrict__ refs4) {
  int g = blockIdx.x * BLOCK + threadIdx.x;  // 0..BN-1
  float x = xyz[3 * g + 0], y = xyz[3 * g + 1], z = xyz[3 * g + 2];
  float hpp = 0.5f * fmaf(x, x, fmaf(y, y, z * z));
  refs4[g] = make_float4(x, y, z, hpp);
}

// pairs[s*BN + b*NN + q] = 0.5 * min_{r in seg s, r != q} d2(q,r)
// Self-pair (d2 == 0 exactly) is excluded: it contributes sqrt(EPSF) to dsum,
// added analytically in merge. Only 1/8 of blocks contain self-pairs; those
// run a top-2 path and emit m2 (best other) for the affected 128 queries.
template <int NSEG>
__global__ __launch_bounds__(BLOCK, 8) void knn_kernel(
    const float4* __restrict__ refs4, float* __restrict__ pairs) {
  constexpr int SEG = NN / NSEG;
  constexpr int CHUNKS = NN / QB;
  constexpr int U = 8;  // refs per pipeline stage (2x s_load_dwordx16)
  int bid = blockIdx.x;
  int s = bid % NSEG;
  int rem = bid / NSEG;
  int qchunk = rem % CHUNKS;
  int b = rem / CHUNKS;

  const float4* __restrict__ qb4 = refs4 + (size_t)b * NN;

  float nqx[QPT], nqy[QPT], nqz[QPT], hq[QPT], m1[QPT], m2[QPT];
#pragma unroll
  for (int i = 0; i < QPT; i++) {
    int q = qchunk * QB + threadIdx.x + i * BLOCK;
    float4 qp = qb4[q];  // coalesced vector load
    nqx[i] = -qp.x;
    nqy[i] = -qp.y;
    nqz[i] = -qp.z;
    hq[i] = qp.w;
    m1[i] = BIGF;
    m2[i] = BIGF;
  }

  // wave-uniform ref stream -> scalar loads, software-pipelined double buffer.
  const float4* __restrict__ rp = qb4 + s * SEG;
  const bool self_block = ((s * SEG) / QB) == qchunk;

  float4 cur[U];
#pragma unroll
  for (int u = 0; u < U; u++) cur[u] = rp[u];

  if (!self_block) {
    // top-1 path: 2 refs per min3 -> 3.75 VALU/pair incl. pw movs
    for (int j0 = 0; j0 < SEG; j0 += U) {
      int jn = (j0 + U < SEG) ? (j0 + U) : 0;
      float4 nxt[U];
#pragma unroll
      for (int u = 0; u < U; u++) nxt[u] = rp[jn + u];

#pragma unroll
      for (int u = 0; u < U; u += 2) {
        float4 p0 = cur[u], p1 = cur[u + 1];
        float pw0 = p0.w, pw1 = p1.w;  // VGPR copies: 1 SGPR operand per fma
#pragma unroll
        for (int i = 0; i < QPT; i++) {
          float t0 = fmaf(nqx[i], p0.x, pw0);
          t0 = fmaf(nqy[i], p0.y, t0);
          t0 = fmaf(nqz[i], p0.z, t0);
          float t1 = fmaf(nqx[i], p1.x, pw1);
          t1 = fmaf(nqy[i], p1.y, t1);
          t1 = fmaf(nqz[i], p1.z, t1);
          m1[i] = fmin3f(m1[i], t0, t1);
        }
      }
#pragma unroll
      for (int u = 0; u < U; u++) cur[u] = nxt[u];
    }
  } else {
    // top-2 path (self lands in m1 as exact segment minimum; m2 = best other)
    for (int j0 = 0; j0 < SEG; j0 += U) {
      int jn = (j0 + U < SEG) ? (j0 + U) : 0;
      float4 nxt[U];
#pragma unroll
      for (int u = 0; u < U; u++) nxt[u] = rp[jn + u];

#pragma unroll
      for (int u = 0; u < U; u += 2) {
        float4 p0 = cur[u], p1 = cur[u + 1];
        float pw0 = p0.w, pw1 = p1.w;
#pragma unroll
        for (int i = 0; i < QPT; i++) {
          float t0 = fmaf(nqx[i], p0.x, pw0);
          t0 = fmaf(nqy[i], p0.y, t0);
          t0 = fmaf(nqz[i], p0.z, t0);
          float t1 = fmaf(nqx[i], p1.x, pw1);
          t1 = fmaf(nqy[i], p1.y, t1);
          t1 = fmaf(nqz[i], p1.z, t1);
          // second-smallest of {m1,m2,t0,t1} = min(m2, med3(m1,t0,t1))
          float med = __builtin_amdgcn_fmed3f(m1[i], t0, t1);  // old m1
          m2[i] = fminf(m2[i], med);
          m1[i] = fmin3f(m1[i], t0, t1);
        }
      }
#pragma unroll
      for (int u = 0; u < U; u++) cur[u] = nxt[u];
    }
  }

#pragma unroll
  for (int i = 0; i < QPT; i++) {
    int q = qchunk * QB + threadIdx.x + i * BLOCK;
    float best = m1[i];
    if (self_block && (q / SEG) == s) best = m2[i];  // drop exact self-min
    pairs[(size_t)s * BN + b * NN + q] = best + hq[i];  // un-shift -> d2/2
  }
}

// merge: one thread per point; 256 blocks x 128 threads.
#define MBLK 128
#define NPART (BN / MBLK)  // 256
template <int NSEG>
__global__ __launch_bounds__(MBLK) void merge_kernel(
    const float* __restrict__ pairs, float* __restrict__ dsum,
    float* __restrict__ partial) {
  int g = blockIdx.x * MBLK + threadIdx.x;  // 0 .. BN-1
  float m = BIGF;
#pragma unroll 8
  for (int s = 0; s < NSEG; s += 2) {
    float a = pairs[(size_t)s * BN + g];
    float c = pairs[(size_t)(s + 1) * BN + g];
    m = fmin3f(m, a, c);
  }
  // self term: reference sqrt(max(0, EPS)) == sqrt(EPSF), exact.
  float ds = sqrtf(fmaxf(m + m, EPSF)) + sqrtf(EPSF);
  dsum[g] = ds;

  float v = ds;
#pragma unroll
  for (int off = 32; off > 0; off >>= 1) v += __shfl_down(v, off, 64);
  __shared__ float warp_sums[MBLK / 64];
  if ((threadIdx.x & 63) == 0) warp_sums[threadIdx.x >> 6] = v;
  __syncthreads();
  if (threadIdx.x == 0) {
    float t = 0.0f;
#pragma unroll
    for (int w = 0; w < MBLK / 64; w++) t += warp_sums[w];
    partial[blockIdx.x] = t;
  }
}

// loss: single block of 1024 threads.
#define LBLK 1024
__global__ __launch_bounds__(LBLK) void loss_kernel(
    const float* __restrict__ dsum, const float* __restrict__ partial,
    float* __restrict__ out) {
  __shared__ float s_avg[BB];
  if (threadIdx.x < NPART) {
    float v = partial[threadIdx.x];  // 64 consecutive partials per batch
#pragma unroll
    for (int off = 32; off > 0; off >>= 1) v += __shfl_down(v, off, 64);
    if ((threadIdx.x & 63) == 0) s_avg[threadIdx.x >> 6] = v * (ALPHA / NN);
  }
  __syncthreads();

  const float4* d4 = (const float4*)dsum;
  float acc = 0.0f;
#pragma unroll
  for (int it = 0; it < BN / (LBLK * 4); it++) {
    int idx = it * LBLK + threadIdx.x;  // float4 index
    float4 v = d4[idx];
    float thr = s_avg[idx >> 11];       // 2048 float4 per batch
    acc += (v.x > thr) ? v.x : 0.0f;
    acc += (v.y > thr) ? v.y : 0.0f;
    acc += (v.z > thr) ? v.z : 0.0f;
    acc += (v.w > thr) ? v.w : 0.0f;
  }
#pragma unroll
  for (int off = 32; off > 0; off >>= 1) acc += __shfl_down(acc, off, 64);
  __shared__ float warp_sums[LBLK / 64];
  if ((threadIdx.x & 63) == 0) warp_sums[threadIdx.x >> 6] = acc;
  __syncthreads();
  if (threadIdx.x == 0) {
    float t = 0.0f;
#pragma unroll
    for (int w = 0; w < LBLK / 64; w++) t += warp_sums[w];
    out[0] = t;
  }
}

template <int NSEG>
static void run(const float* xyz, float* out, void* d_ws, hipStream_t stream) {
  float* pairs = (float*)d_ws;
  float4* refs4 = (float4*)(pairs + (size_t)NSEG * BN);
  float* dsum = (float*)(refs4 + BN);
  float* partial = dsum + BN;
  prep_kernel<<<BN / BLOCK, BLOCK, 0, stream>>>(xyz, refs4);
  int grid1 = BB * (NN / QB) * NSEG;
  knn_kernel<NSEG><<<grid1, BLOCK, 0, stream>>>(refs4, pairs);
  merge_kernel<NSEG><<<BN / MBLK, MBLK, 0, stream>>>(pairs, dsum, partial);
  loss_kernel<<<1, LBLK, 0, stream>>>(dsum, partial, out);
}

extern "C" void kernel_launch(void* const* d_in, const int* in_sizes, int n_in,
                              void* d_out, int out_size, void* d_ws,
                              size_t ws_size, hipStream_t stream) {
  const float* xyz = (const float*)d_in[0];
  float* out = (float*)d_out;

  auto need = [](int nseg) {
    return (size_t)nseg * BN * sizeof(float) + BN * sizeof(float4) +
           BN * sizeof(float) + NPART * sizeof(float);
  };
  if (ws_size >= need(64)) {
    run<64>(xyz, out, d_ws, stream);  // grid1 = 2048 blocks, 8/CU
  } else if (ws_size >= need(32)) {
    run<32>(xyz, out, d_ws, stream);
  } else {
    run<16>(xyz, out, d_ws, stream);
  }
}